// Round 15
// baseline (170.764 us; speedup 1.0000x reference)
//
#include <hip/hip_runtime.h>
#include <cfloat>
#include <cmath>

#define B_    8
#define N_    8192
#define M_    2048
#define C1_   128
#define C2_   256
#define CIN_  384
#define H_    256
#define BNEPS 1e-5f
#define TJ    64
#define TJ1   32
#define NBLK1 ((N_ / TJ1) * B_)   // 2048 partial-stat blocks (gemm1)
#define NBLK2 ((N_ / TJ)  * B_)   // 1024 partial-stat blocks (gemm2)

typedef __bf16 bf16x8 __attribute__((ext_vector_type(8)));
typedef float  f32x4  __attribute__((ext_vector_type(4)));

__device__ __forceinline__ bool lexless(float d, int m, float dk, int ik) {
    return (d < dk) | ((d == dk) & (m < ik));
}
__device__ __forceinline__ void ins3(float d, int m,
                                     float& d0, int& i0, float& d1, int& i1,
                                     float& d2, int& i2) {
    if (lexless(d, m, d2, i2)) {
        if (lexless(d, m, d1, i1)) {
            d2 = d1; i2 = i1;
            if (lexless(d, m, d0, i0)) { d1 = d0; i1 = i0; d0 = d; i0 = m; }
            else                       { d1 = d;  i1 = m; }
        } else { d2 = d; i2 = m; }
    }
}

// ---------------------------------------------------------------- KNN (k=3)
// 4 thr/query, interleaved slices (m = 4*it + q). Exact fp32 distances,
// med3 network + 5-cndmask index tracking; lex merge across the quad.
// NOTE: distance formula byte-identical to the passing r8-r14 versions —
// selection numerics must not be perturbed (r7 lesson).
__global__ __launch_bounds__(256) void knn_kernel(const float* __restrict__ xyz1,
                                                  const float* __restrict__ xyz2,
                                                  float* __restrict__ wsW,
                                                  int* __restrict__ wsI) {
    __shared__ float4 pts[M_];                      // 32 KB: x,y,z,|p|^2
    const int b = blockIdx.y;
    const int t = threadIdx.x;
    const int n = blockIdx.x * 64 + (t >> 2);
    const int q = t & 3;

    const float* x2 = xyz2 + (size_t)b * 3 * M_;
    for (int m = t; m < M_; m += 256) {
        float x = x2[m], y = x2[M_ + m], z = x2[2 * M_ + m];
        pts[m] = make_float4(x, y, z, fmaf(z, z, fmaf(y, y, x * x)));
    }
    __syncthreads();

    const float* x1 = xyz1 + (size_t)b * 3 * N_;
    const float px = x1[n], py = x1[N_ + n], pz = x1[2 * N_ + n];
    const float s1 = fmaf(pz, pz, fmaf(py, py, px * px));
    const float ax = -2.0f * px, ay = -2.0f * py, az = -2.0f * pz;

    float d0 = FLT_MAX, d1 = FLT_MAX, d2 = FLT_MAX;
    int   i0 = 0x7fffffff, i1 = 0x7fffffff, i2 = 0x7fffffff;

    const float4* p = pts + q;
    #pragma unroll 8
    for (int it = 0; it < M_ / 4; ++it) {
        const float4 pt = p[it * 4];
        const float d = fmaf(ax, pt.x, fmaf(ay, pt.y, fmaf(az, pt.z, s1 + pt.w)));
        const int m = it * 4 + q;
        const bool c0 = d < d0, c1 = d < d1, c2 = d < d2;
        i2 = c1 ? i1 : (c2 ? m : i2);
        i1 = c0 ? i0 : (c1 ? m : i1);
        i0 = c0 ? m  : i0;
        d2 = __builtin_amdgcn_fmed3f(d, d1, d2);
        d1 = __builtin_amdgcn_fmed3f(d, d0, d1);
        d0 = fminf(d, d0);
    }

    #pragma unroll
    for (int delta = 1; delta <= 2; delta <<= 1) {
        float e0 = __shfl_xor(d0, delta), e1 = __shfl_xor(d1, delta), e2 = __shfl_xor(d2, delta);
        int   j0 = __shfl_xor(i0, delta), j1 = __shfl_xor(i1, delta), j2 = __shfl_xor(i2, delta);
        ins3(e0, j0, d0, i0, d1, i1, d2, i2);
        ins3(e1, j1, d0, i0, d1, i1, d2, i2);
        ins3(e2, j2, d0, i0, d1, i1, d2, i2);
    }

    if (q == 0) {
        const float e0 = fmaxf(d0, 1e-10f) + 1e-8f;
        const float e1 = fmaxf(d1, 1e-10f) + 1e-8f;
        const float e2 = fmaxf(d2, 1e-10f) + 1e-8f;
        const float r0 = 1.0f / e0, r1 = 1.0f / e1, r2 = 1.0f / e2;
        const float sum = r0 + r1 + r2;
        const int BNtot = B_ * N_;
        const int base  = b * N_ + n;
        wsW[base] = r0 / sum;  wsW[BNtot + base] = r1 / sum;  wsW[2 * BNtot + base] = r2 / sum;
        wsI[base] = i0;        wsI[BNtot + base] = i1;        wsI[2 * BNtot + base] = i2;
    }
}

// ------------------------------------------- transpose points2 -> p2t[b][m][c] BF16
__global__ __launch_bounds__(256) void tp2_kernel(const float* __restrict__ p2,
                                                  __bf16* __restrict__ p2t) {
    __shared__ float tile[32][33];
    const int b  = blockIdx.z;
    const int c0 = blockIdx.x * 32, m0 = blockIdx.y * 32;
    const int tx = threadIdx.x & 31, ty = threadIdx.x >> 5;
    const float* src = p2 + ((size_t)b * C2_ + c0) * M_ + m0;
    #pragma unroll
    for (int r = 0; r < 32; r += 8) tile[ty + r][tx] = src[(size_t)(ty + r) * M_ + tx];
    __syncthreads();
    __bf16* dst = p2t + ((size_t)b * M_ + m0) * C2_ + c0;
    #pragma unroll
    for (int r = 0; r < 32; r += 8) dst[(size_t)(ty + r) * C2_ + tx] = (__bf16)tile[tx][ty + r];
}

// ------------------------------------------- pack W into A-frag layout
__global__ __launch_bounds__(256) void packW_kernel(const float* __restrict__ W,
                                                    unsigned short* __restrict__ Wp,
                                                    int Cin) {
    const int tid = blockIdx.x * 256 + threadIdx.x;
    const int total = (Cin / 32) * 16 * 64;
    if (tid >= total) return;
    const int lane = tid & 63;
    const int ob   = (tid >> 6) & 15;
    const int kc   = tid >> 10;
    const int row  = ob * 16 + (lane & 15);
    const int k0   = kc * 32 + (lane >> 4) * 8;
    const float* src = W + (size_t)row * Cin + k0;
    __bf16* dst = (__bf16*)(Wp + (size_t)tid * 8);
    #pragma unroll
    for (int e = 0; e < 8; ++e) dst[e] = (__bf16)src[e];
}

// ------------------------------------------- GEMM1: interp+concat fused, bf16 MFMA.
// TJ1=32 cols, 128-thr blocks (2 waves x 128 rows), grid 2048 (8/CU),
// 3-deep staging pipeline (2 reg stages + 3 LDS buffers), bf16 gathers,
// fused BN partials, bf16 output panel.
__global__ __launch_bounds__(128, 2) void gemm1_kernel(const float* __restrict__ points1,
                                                       const __bf16* __restrict__ p2t,
                                                       const bf16x8* __restrict__ W1f,
                                                       const float* __restrict__ bias1,
                                                       const float* __restrict__ wsW,
                                                       const int* __restrict__ wsI,
                                                       __bf16* __restrict__ Y1bf,
                                                       float* __restrict__ partS,
                                                       float* __restrict__ partS2) {
    __shared__ __align__(16) unsigned short Bfrag[3][2][64][8];   // 6 KB triple buffer
    __shared__ float wsh[3][TJ1];
    __shared__ int   ish[3][TJ1];

    const int b  = blockIdx.y;
    const int n0 = blockIdx.x * TJ1;
    const int t  = threadIdx.x;                 // 0..127
    const int wave = t >> 6, lane = t & 63;
    const int pid  = b * (N_ / TJ1) + blockIdx.x;
    const int BNtot = B_ * N_;

    if (t < 3 * TJ1) {
        int k = t >> 5, j = t & 31;
        wsh[k][j] = wsW[k * BNtot + b * N_ + n0 + j];
        ish[k][j] = wsI[k * BNtot + b * N_ + n0 + j];
    }
    __syncthreads();

    const int j = t >> 2, q = t & 3;            // j in [0,32), q in [0,4)
    const float w0 = wsh[0][j], w1 = wsh[1][j], w2 = wsh[2][j];
    const __bf16* r0 = p2t + ((size_t)(b * M_ + ish[0][j])) * C2_;
    const __bf16* r1 = p2t + ((size_t)(b * M_ + ish[1][j])) * C2_;
    const __bf16* r2 = p2t + ((size_t)(b * M_ + ish[2][j])) * C2_;
    const float* p1b = points1 + (size_t)b * C1_ * N_ + n0 + j;
    uint4* dstB[3] = { (uint4*)&Bfrag[0][j >> 4][q * 16 + (j & 15)][0],
                       (uint4*)&Bfrag[1][j >> 4][q * 16 + (j & 15)][0],
                       (uint4*)&Bfrag[2][j >> 4][q * 16 + (j & 15)][0] };

    struct Stage { bf16x8 a, b, c; float f[8]; };
    auto issue = [&](int kc, Stage& S) {
        if (kc < C2_ / 32) {
            const int off = kc * 32 + q * 8;
            S.a = *(const bf16x8*)(r0 + off);
            S.b = *(const bf16x8*)(r1 + off);
            S.c = *(const bf16x8*)(r2 + off);
        } else {
            const int cbase = kc * 32 - C2_ + q * 8;
            #pragma unroll
            for (int e = 0; e < 8; ++e) S.f[e] = p1b[(size_t)(cbase + e) * N_];
        }
    };
    auto packwrite = [&](int kc, const Stage& S, uint4* dst) {
        union { __bf16 h[8]; uint4 u4; } pk;
        if (kc < C2_ / 32) {
            #pragma unroll
            for (int e = 0; e < 8; ++e)
                pk.h[e] = (__bf16)fmaf(w2, (float)S.c[e],
                               fmaf(w1, (float)S.b[e], w0 * (float)S.a[e]));
        } else {
            #pragma unroll
            for (int e = 0; e < 8; ++e) pk.h[e] = (__bf16)S.f[e];
        }
        *dst = pk.u4;
    };

    constexpr int NK = CIN_ / 32;               // 12
    f32x4 acc[8][2];
    #pragma unroll
    for (int rb = 0; rb < 8; ++rb) {
        acc[rb][0] = (f32x4){0.f, 0.f, 0.f, 0.f};
        acc[rb][1] = (f32x4){0.f, 0.f, 0.f, 0.f};
    }

    Stage SA, SB;
    bf16x8 afA[8], afB[8];
    issue(0, SA);
    issue(1, SB);
    #pragma unroll
    for (int rb = 0; rb < 8; ++rb)
        afA[rb] = W1f[((size_t)0 * 16 + wave * 8 + rb) * 64 + lane];
    packwrite(0, SA, dstB[0]);
    __syncthreads();

    #pragma unroll
    for (int kc = 0; kc < NK; ++kc) {
        // issue chunk kc+2 into the stage reg freed last iteration (parity kc&1)
        if (kc + 2 < NK) issue(kc + 2, (kc & 1) ? SB : SA);
        // prefetch W frags for chunk kc+1 into the other parity set
        bf16x8 (&afn)[8] = ((kc + 1) & 1) ? afB : afA;
        if (kc + 1 < NK) {
            #pragma unroll
            for (int rb = 0; rb < 8; ++rb)
                afn[rb] = W1f[((size_t)(kc + 1) * 16 + wave * 8 + rb) * 64 + lane];
        }
        // MFMA on chunk kc
        bf16x8 (&afc)[8] = (kc & 1) ? afB : afA;
        const bf16x8 bfr0 = *reinterpret_cast<const bf16x8*>(&Bfrag[kc % 3][0][lane][0]);
        const bf16x8 bfr1 = *reinterpret_cast<const bf16x8*>(&Bfrag[kc % 3][1][lane][0]);
        #pragma unroll
        for (int rb = 0; rb < 8; ++rb) {
            acc[rb][0] = __builtin_amdgcn_mfma_f32_16x16x32_bf16(afc[rb], bfr0, acc[rb][0], 0, 0, 0);
            acc[rb][1] = __builtin_amdgcn_mfma_f32_16x16x32_bf16(afc[rb], bfr1, acc[rb][1], 0, 0, 0);
        }
        // pack chunk kc+1 into its LDS buffer
        if (kc + 1 < NK) packwrite(kc + 1, (kc & 1) ? SA : SB, dstB[(kc + 1) % 3]);
        __syncthreads();
    }

    const int rrow = (lane >> 4) * 4, col = lane & 15;
    #pragma unroll
    for (int rb = 0; rb < 8; ++rb) {
        #pragma unroll
        for (int r = 0; r < 4; ++r) {
            const int o = wave * 128 + rb * 16 + rrow + r;
            const float bv = bias1[o];
            float s = 0.f, s2 = 0.f;
            #pragma unroll
            for (int nb = 0; nb < 2; ++nb) {
                float val = acc[rb][nb][r] + bv;
                Y1bf[((size_t)b * H_ + o) * N_ + n0 + nb * 16 + col] = (__bf16)val;
                s += val;
                s2 = fmaf(val, val, s2);
            }
            #pragma unroll
            for (int delta = 1; delta < 16; delta <<= 1) {
                s  += __shfl_xor(s, delta);
                s2 += __shfl_xor(s2, delta);
            }
            if (col == 0) {
                partS [(size_t)o * NBLK1 + pid] = s;
                partS2[(size_t)o * NBLK1 + pid] = s2;
            }
        }
    }
}

// ------------------------------------------- reduce partials -> scale/shift
__global__ __launch_bounds__(256) void reduce_stats(const float* __restrict__ partS,
                                                    const float* __restrict__ partS2,
                                                    const float* __restrict__ g,
                                                    const float* __restrict__ beta,
                                                    float* __restrict__ sc,
                                                    float* __restrict__ sh,
                                                    int nblk) {
    const int c = blockIdx.x;
    const int t = threadIdx.x;
    double s = 0.0, s2 = 0.0;
    for (int i = t; i < nblk; i += 256) {
        s  += (double)partS [(size_t)c * nblk + i];
        s2 += (double)partS2[(size_t)c * nblk + i];
    }
    __shared__ double ls[256], ls2[256];
    ls[t] = s; ls2[t] = s2;
    __syncthreads();
    for (int off = 128; off > 0; off >>= 1) {
        if (t < off) { ls[t] += ls[t + off]; ls2[t] += ls2[t + off]; }
        __syncthreads();
    }
    if (t == 0) {
        const double cnt = (double)B_ * N_;
        double mean = ls[0] / cnt;
        double var  = ls2[0] / cnt - mean * mean;
        float rstd  = (float)(1.0 / sqrt(var + (double)BNEPS));
        float scale = rstd * g[c];
        sc[c] = scale;
        sh[c] = beta[c] - (float)mean * scale;
    }
}

// ------------------------------------------- GEMM2: BN1+ReLU on load, bf16 in/out,
// in-place on the bf16 panel, 2-deep pipelined staging, fused BN partials
__global__ __launch_bounds__(256, 2) void gemm2_kernel(const bf16x8* __restrict__ W2f,
                                                       const float* __restrict__ bias2,
                                                       const float* __restrict__ sc1,
                                                       const float* __restrict__ sh1,
                                                       __bf16* __restrict__ Ybf,
                                                       float* __restrict__ partS,
                                                       float* __restrict__ partS2) {
    __shared__ __align__(16) unsigned short Bfrag[2][4][64][8];
    __shared__ float scs[H_], shs[H_];

    const int b  = blockIdx.y;
    const int n0 = blockIdx.x * TJ;
    const int t  = threadIdx.x;
    const int wave = t >> 6, lane = t & 63;
    const int pid  = b * (N_ / TJ) + blockIdx.x;

    scs[t] = sc1[t];
    shs[t] = sh1[t];
    __syncthreads();

    const int j = t >> 2, q = t & 3;
    __bf16* Yb = Ybf + (size_t)b * H_ * N_;
    const __bf16* src = Yb + n0 + j;
    uint4* dstB[2] = { (uint4*)&Bfrag[0][j >> 4][q * 16 + (j & 15)][0],
                       (uint4*)&Bfrag[1][j >> 4][q * 16 + (j & 15)][0] };

    auto issue = [&](int kc, float L[8]) {
        #pragma unroll
        for (int e = 0; e < 8; ++e)
            L[e] = (float)src[(size_t)(kc * 32 + q * 8 + e) * N_];
    };
    auto packwrite = [&](int kc, const float L[8], uint4* dst) {
        union { __bf16 h[8]; uint4 u4; } pk;
        #pragma unroll
        for (int e = 0; e < 8; ++e) {
            const int c = kc * 32 + q * 8 + e;
            pk.h[e] = (__bf16)fmaxf(fmaf(L[e], scs[c], shs[c]), 0.0f);
        }
        *dst = pk.u4;
    };

    f32x4 acc[4][4];
    #pragma unroll
    for (int rb = 0; rb < 4; ++rb)
        #pragma unroll
        for (int nb = 0; nb < 4; ++nb) acc[rb][nb] = (f32x4){0.f, 0.f, 0.f, 0.f};

    float L[8];
    bf16x8 af[4], afn[4];
    issue(0, L);
    #pragma unroll
    for (int rb = 0; rb < 4; ++rb)
        af[rb] = W2f[((size_t)0 * 16 + wave * 4 + rb) * 64 + lane];
    packwrite(0, L, dstB[0]);
    __syncthreads();

    #pragma unroll
    for (int kc = 0; kc < H_ / 32; ++kc) {
        constexpr int NK = H_ / 32;
        float Ln[8];
        if (kc + 1 < NK) {
            issue(kc + 1, Ln);
            #pragma unroll
            for (int rb = 0; rb < 4; ++rb)
                afn[rb] = W2f[((size_t)(kc + 1) * 16 + wave * 4 + rb) * 64 + lane];
        }
        bf16x8 bfr[4];
        #pragma unroll
        for (int nb = 0; nb < 4; ++nb)
            bfr[nb] = *reinterpret_cast<const bf16x8*>(&Bfrag[kc & 1][nb][lane][0]);
        #pragma unroll
        for (int rb = 0; rb < 4; ++rb)
            #pragma unroll
            for (int nb = 0; nb < 4; ++nb)
                acc[rb][nb] = __builtin_amdgcn_mfma_f32_16x16x32_bf16(af[rb], bfr[nb],
                                                                      acc[rb][nb], 0, 0, 0);
        if (kc + 1 < NK) {
            packwrite(kc + 1, Ln, dstB[(kc + 1) & 1]);
            #pragma unroll
            for (int rb = 0; rb < 4; ++rb) af[rb] = afn[rb];
        }
        __syncthreads();
    }

    const int rrow = (lane >> 4) * 4, col = lane & 15;
    #pragma unroll
    for (int rb = 0; rb < 4; ++rb) {
        #pragma unroll
        for (int r = 0; r < 4; ++r) {
            const int o = wave * 64 + rb * 16 + rrow + r;
            const float bv = bias2[o];
            float s = 0.f, s2 = 0.f;
            #pragma unroll
            for (int nb = 0; nb < 4; ++nb) {
                float val = acc[rb][nb][r] + bv;
                Yb[(size_t)o * N_ + n0 + nb * 16 + col] = (__bf16)val;
                s += val;
                s2 = fmaf(val, val, s2);
            }
            #pragma unroll
            for (int delta = 1; delta < 16; delta <<= 1) {
                s  += __shfl_xor(s, delta);
                s2 += __shfl_xor(s2, delta);
            }
            if (col == 0) {
                partS [(size_t)o * NBLK2 + pid] = s;
                partS2[(size_t)o * NBLK2 + pid] = s2;
            }
        }
    }
}

// ------------------------------------------- final BN2+ReLU: bf16 in -> f32 out
__global__ __launch_bounds__(256) void bnrelu_kernel(const __bf16* __restrict__ Ybf,
                                                     float* __restrict__ out,
                                                     const float* __restrict__ sc,
                                                     const float* __restrict__ sh) {
    const size_t total8 = (size_t)B_ * H_ * N_ / 8;
    const size_t stride = (size_t)gridDim.x * 256;
    for (size_t i = (size_t)blockIdx.x * 256 + threadIdx.x; i < total8; i += stride) {
        bf16x8 v = ((const bf16x8*)Ybf)[i];
        const int c = (int)((i / (N_ / 8)) % H_);
        const float a = sc[c], d = sh[c];
        float4 lo, hi;
        lo.x = fmaxf(fmaf((float)v[0], a, d), 0.f);
        lo.y = fmaxf(fmaf((float)v[1], a, d), 0.f);
        lo.z = fmaxf(fmaf((float)v[2], a, d), 0.f);
        lo.w = fmaxf(fmaf((float)v[3], a, d), 0.f);
        hi.x = fmaxf(fmaf((float)v[4], a, d), 0.f);
        hi.y = fmaxf(fmaf((float)v[5], a, d), 0.f);
        hi.z = fmaxf(fmaf((float)v[6], a, d), 0.f);
        hi.w = fmaxf(fmaf((float)v[7], a, d), 0.f);
        ((float4*)out)[i * 2]     = lo;
        ((float4*)out)[i * 2 + 1] = hi;
    }
}

// ---------------------------------------------------------------- launch
extern "C" void kernel_launch(void* const* d_in, const int* in_sizes, int n_in,
                              void* d_out, int out_size, void* d_ws, size_t ws_size,
                              hipStream_t stream) {
    const float* xyz1    = (const float*)d_in[0];
    const float* xyz2    = (const float*)d_in[1];
    const float* points1 = (const float*)d_in[2];
    const float* points2 = (const float*)d_in[3];
    const float* W1      = (const float*)d_in[4];
    const float* b1      = (const float*)d_in[5];
    const float* g1      = (const float*)d_in[6];
    const float* beta1   = (const float*)d_in[7];
    const float* W2      = (const float*)d_in[8];
    const float* b2      = (const float*)d_in[9];
    const float* g2      = (const float*)d_in[10];
    const float* beta2   = (const float*)d_in[11];
    float* out = (float*)d_out;

    const int BNtot = B_ * N_;
    char* ws = (char*)d_ws;
    size_t off = 0;
    float* wsW = (float*)(ws + off);  off += (size_t)3 * BNtot * 4;
    int*   wsI = (int*)(ws + off);    off += (size_t)3 * BNtot * 4;
    float* sc1 = (float*)(ws + off);  off += H_ * 4;
    float* sh1 = (float*)(ws + off);  off += H_ * 4;
    float* sc2 = (float*)(ws + off);  off += H_ * 4;
    float* sh2 = (float*)(ws + off);  off += H_ * 4;
    __bf16* p2t = (__bf16*)(ws + off); off += (size_t)B_ * M_ * C2_ * 2;     // 8.4 MB
    unsigned short* W1p = (unsigned short*)(ws + off); off += (size_t)H_ * CIN_ * 2;
    unsigned short* W2p = (unsigned short*)(ws + off); off += (size_t)H_ * H_ * 2;
    float* partS  = (float*)(ws + off); off += (size_t)H_ * NBLK1 * 4;       // 2 MB
    float* partS2 = (float*)(ws + off); off += (size_t)H_ * NBLK1 * 4;       // 2 MB
    __bf16* ybf   = (__bf16*)(ws + off); off += (size_t)B_ * H_ * N_ * 2;    // 33.5 MB

    knn_kernel<<<dim3(N_ / 64, B_), 256, 0, stream>>>(xyz1, xyz2, wsW, wsI);
    tp2_kernel<<<dim3(C2_ / 32, M_ / 32, B_), 256, 0, stream>>>(points2, p2t);
    packW_kernel<<<(CIN_ / 32 * 16 * 64 + 255) / 256, 256, 0, stream>>>(W1, W1p, CIN_);
    packW_kernel<<<(H_ / 32 * 16 * 64 + 255) / 256, 256, 0, stream>>>(W2, W2p, H_);

    gemm1_kernel<<<dim3(N_ / TJ1, B_), 128, 0, stream>>>(points1, p2t, (const bf16x8*)W1p,
                                                         b1, wsW, wsI, ybf, partS, partS2);
    reduce_stats<<<H_, 256, 0, stream>>>(partS, partS2, g1, beta1, sc1, sh1, NBLK1);
    gemm2_kernel<<<dim3(N_ / TJ, B_), 256, 0, stream>>>((const bf16x8*)W2p, b2, sc1, sh1,
                                                        ybf, partS, partS2);
    reduce_stats<<<H_, 256, 0, stream>>>(partS, partS2, g2, beta2, sc2, sh2, NBLK2);
    bnrelu_kernel<<<4096, 256, 0, stream>>>(ybf, out, sc2, sh2);
}

// Round 16
// 146.787 us; speedup vs baseline: 1.1633x; 1.1633x over previous
//
#include <hip/hip_runtime.h>
#include <cfloat>
#include <cmath>

#define B_    8
#define N_    8192
#define M_    2048
#define C1_   128
#define C2_   256
#define CIN_  384
#define H_    256
#define BNEPS 1e-5f
#define TJ    64
#define NBLK  ((N_ / TJ) * B_)   // 1024 partial-stat blocks per GEMM

typedef __bf16 bf16x8 __attribute__((ext_vector_type(8)));
typedef float  f32x4  __attribute__((ext_vector_type(4)));

__device__ __forceinline__ bool lexless(float d, int m, float dk, int ik) {
    return (d < dk) | ((d == dk) & (m < ik));
}
__device__ __forceinline__ void ins3(float d, int m,
                                     float& d0, int& i0, float& d1, int& i1,
                                     float& d2, int& i2) {
    if (lexless(d, m, d2, i2)) {
        if (lexless(d, m, d1, i1)) {
            d2 = d1; i2 = i1;
            if (lexless(d, m, d0, i0)) { d1 = d0; i1 = i0; d0 = d; i0 = m; }
            else                       { d1 = d;  i1 = m; }
        } else { d2 = d; i2 = m; }
    }
}

// ------------------------------------------- transpose points2 -> p2t[b][m][c] BF16
__global__ __launch_bounds__(256) void tp2_kernel(const float* __restrict__ p2,
                                                  __bf16* __restrict__ p2t) {
    __shared__ float tile[32][33];
    const int b  = blockIdx.z;
    const int c0 = blockIdx.x * 32, m0 = blockIdx.y * 32;
    const int tx = threadIdx.x & 31, ty = threadIdx.x >> 5;
    const float* src = p2 + ((size_t)b * C2_ + c0) * M_ + m0;
    #pragma unroll
    for (int r = 0; r < 32; r += 8) tile[ty + r][tx] = src[(size_t)(ty + r) * M_ + tx];
    __syncthreads();
    __bf16* dst = p2t + ((size_t)b * M_ + m0) * C2_ + c0;
    #pragma unroll
    for (int r = 0; r < 32; r += 8) dst[(size_t)(ty + r) * C2_ + tx] = (__bf16)tile[tx][ty + r];
}

// ------------------------------------------- pack W into A-frag layout
__global__ __launch_bounds__(256) void packW_kernel(const float* __restrict__ W,
                                                    unsigned short* __restrict__ Wp,
                                                    int Cin) {
    const int tid = blockIdx.x * 256 + threadIdx.x;
    const int total = (Cin / 32) * 16 * 64;
    if (tid >= total) return;
    const int lane = tid & 63;
    const int ob   = (tid >> 6) & 15;
    const int kc   = tid >> 10;
    const int row  = ob * 16 + (lane & 15);
    const int k0   = kc * 32 + (lane >> 4) * 8;
    const float* src = W + (size_t)row * Cin + k0;
    __bf16* dst = (__bf16*)(Wp + (size_t)tid * 8);
    #pragma unroll
    for (int e = 0; e < 8; ++e) dst[e] = (__bf16)src[e];
}

// ------------------------------------------- FUSED KNN + GEMM1
// Phase A (knn): this block's 64 queries, 4 thr/query, exact fp32 selection
// (byte-identical numerics to the passing r8-r14 versions), results -> LDS.
// Phase B (gemm1): r14 structure — interp+concat staged bf16, 2-deep pipeline,
// double-buffered LDS, MFMA, fused BN partials, bf16 output panel.
// pts (32 KB, phase A) aliases Bfrag (8 KB, phase B) via union.
__global__ __launch_bounds__(256, 2) void knn_gemm1_kernel(const float* __restrict__ xyz1,
                                                           const float* __restrict__ xyz2,
                                                           const float* __restrict__ points1,
                                                           const __bf16* __restrict__ p2t,
                                                           const bf16x8* __restrict__ W1f,
                                                           const float* __restrict__ bias1,
                                                           __bf16* __restrict__ Y1bf,
                                                           float* __restrict__ partS,
                                                           float* __restrict__ partS2) {
    union SharedU {
        float4 pts[M_];                              // 32 KB (phase A)
        unsigned short Bfrag[2][4][64][8];           //  8 KB (phase B)
    };
    __shared__ SharedU su;
    __shared__ float wsh[3][TJ];
    __shared__ int   ish[3][TJ];

    const int b  = blockIdx.y;
    const int n0 = blockIdx.x * TJ;
    const int t  = threadIdx.x;
    const int wave = t >> 6, lane = t & 63;
    const int pid  = b * (N_ / TJ) + blockIdx.x;
    const int j = t >> 2, q = t & 3;                 // shared role: query/column j, quarter q

    // ================= Phase A: KNN for this block's 64 queries =================
    {
        const float* x2 = xyz2 + (size_t)b * 3 * M_;
        for (int m = t; m < M_; m += 256) {
            float x = x2[m], y = x2[M_ + m], z = x2[2 * M_ + m];
            su.pts[m] = make_float4(x, y, z, fmaf(z, z, fmaf(y, y, x * x)));
        }
        __syncthreads();

        const int n = n0 + j;
        const float* x1 = xyz1 + (size_t)b * 3 * N_;
        const float px = x1[n], py = x1[N_ + n], pz = x1[2 * N_ + n];
        const float s1 = fmaf(pz, pz, fmaf(py, py, px * px));
        const float ax = -2.0f * px, ay = -2.0f * py, az = -2.0f * pz;

        float d0 = FLT_MAX, d1 = FLT_MAX, d2 = FLT_MAX;
        int   i0 = 0x7fffffff, i1 = 0x7fffffff, i2 = 0x7fffffff;

        const float4* p = su.pts + q;
        #pragma unroll 8
        for (int it = 0; it < M_ / 4; ++it) {
            const float4 pt = p[it * 4];
            const float d = fmaf(ax, pt.x, fmaf(ay, pt.y, fmaf(az, pt.z, s1 + pt.w)));
            const int m = it * 4 + q;
            const bool c0 = d < d0, c1 = d < d1, c2 = d < d2;
            i2 = c1 ? i1 : (c2 ? m : i2);
            i1 = c0 ? i0 : (c1 ? m : i1);
            i0 = c0 ? m  : i0;
            d2 = __builtin_amdgcn_fmed3f(d, d1, d2);
            d1 = __builtin_amdgcn_fmed3f(d, d0, d1);
            d0 = fminf(d, d0);
        }

        #pragma unroll
        for (int delta = 1; delta <= 2; delta <<= 1) {
            float e0 = __shfl_xor(d0, delta), e1 = __shfl_xor(d1, delta), e2 = __shfl_xor(d2, delta);
            int   j0 = __shfl_xor(i0, delta), j1 = __shfl_xor(i1, delta), j2 = __shfl_xor(i2, delta);
            ins3(e0, j0, d0, i0, d1, i1, d2, i2);
            ins3(e1, j1, d0, i0, d1, i1, d2, i2);
            ins3(e2, j2, d0, i0, d1, i1, d2, i2);
        }

        if (q == 0) {
            const float e0 = fmaxf(d0, 1e-10f) + 1e-8f;
            const float e1 = fmaxf(d1, 1e-10f) + 1e-8f;
            const float e2 = fmaxf(d2, 1e-10f) + 1e-8f;
            const float r0 = 1.0f / e0, r1 = 1.0f / e1, r2 = 1.0f / e2;
            const float sum = r0 + r1 + r2;
            wsh[0][j] = r0 / sum;  wsh[1][j] = r1 / sum;  wsh[2][j] = r2 / sum;
            ish[0][j] = i0;        ish[1][j] = i1;        ish[2][j] = i2;
        }
        __syncthreads();   // wsh/ish visible; pts dead -> Bfrag may overwrite
    }

    // ================= Phase B: GEMM1 (r14 structure) =================
    const float w0 = wsh[0][j], w1 = wsh[1][j], w2 = wsh[2][j];
    const __bf16* r0 = p2t + ((size_t)(b * M_ + ish[0][j])) * C2_;
    const __bf16* r1 = p2t + ((size_t)(b * M_ + ish[1][j])) * C2_;
    const __bf16* r2 = p2t + ((size_t)(b * M_ + ish[2][j])) * C2_;
    const float* p1b = points1 + (size_t)b * C1_ * N_ + n0 + j;
    uint4* dstB[2] = { (uint4*)&su.Bfrag[0][j >> 4][q * 16 + (j & 15)][0],
                       (uint4*)&su.Bfrag[1][j >> 4][q * 16 + (j & 15)][0] };

    struct Stage { bf16x8 a, b, c; float f[8]; };
    auto issue = [&](int kc, Stage& S) {
        if (kc < C2_ / 32) {
            const int off = kc * 32 + q * 8;
            S.a = *(const bf16x8*)(r0 + off);
            S.b = *(const bf16x8*)(r1 + off);
            S.c = *(const bf16x8*)(r2 + off);
        } else {
            const int cbase = kc * 32 - C2_ + q * 8;
            #pragma unroll
            for (int e = 0; e < 8; ++e) S.f[e] = p1b[(size_t)(cbase + e) * N_];
        }
    };
    auto packwrite = [&](int kc, const Stage& S, uint4* dst) {
        union { __bf16 h[8]; uint4 u4; } pk;
        if (kc < C2_ / 32) {
            #pragma unroll
            for (int e = 0; e < 8; ++e)
                pk.h[e] = (__bf16)fmaf(w2, (float)S.c[e],
                               fmaf(w1, (float)S.b[e], w0 * (float)S.a[e]));
        } else {
            #pragma unroll
            for (int e = 0; e < 8; ++e) pk.h[e] = (__bf16)S.f[e];
        }
        *dst = pk.u4;
    };

    f32x4 acc[4][4];
    #pragma unroll
    for (int rb = 0; rb < 4; ++rb)
        #pragma unroll
        for (int nb = 0; nb < 4; ++nb) acc[rb][nb] = (f32x4){0.f, 0.f, 0.f, 0.f};

    Stage L;
    bf16x8 af[4], afn[4];
    issue(0, L);
    #pragma unroll
    for (int rb = 0; rb < 4; ++rb)
        af[rb] = W1f[((size_t)0 * 16 + wave * 4 + rb) * 64 + lane];
    packwrite(0, L, dstB[0]);
    __syncthreads();

    #pragma unroll
    for (int kc = 0; kc < CIN_ / 32; ++kc) {
        constexpr int NK = CIN_ / 32;
        Stage Ln;
        if (kc + 1 < NK) {
            issue(kc + 1, Ln);
            #pragma unroll
            for (int rb = 0; rb < 4; ++rb)
                afn[rb] = W1f[((size_t)(kc + 1) * 16 + wave * 4 + rb) * 64 + lane];
        }
        bf16x8 bfr[4];
        #pragma unroll
        for (int nb = 0; nb < 4; ++nb)
            bfr[nb] = *reinterpret_cast<const bf16x8*>(&su.Bfrag[kc & 1][nb][lane][0]);
        #pragma unroll
        for (int rb = 0; rb < 4; ++rb)
            #pragma unroll
            for (int nb = 0; nb < 4; ++nb)
                acc[rb][nb] = __builtin_amdgcn_mfma_f32_16x16x32_bf16(af[rb], bfr[nb],
                                                                      acc[rb][nb], 0, 0, 0);
        if (kc + 1 < NK) {
            packwrite(kc + 1, Ln, dstB[(kc + 1) & 1]);
            #pragma unroll
            for (int rb = 0; rb < 4; ++rb) af[rb] = afn[rb];
        }
        __syncthreads();
    }

    const int rrow = (lane >> 4) * 4, col = lane & 15;
    #pragma unroll
    for (int rb = 0; rb < 4; ++rb) {
        #pragma unroll
        for (int r = 0; r < 4; ++r) {
            const int o = wave * 64 + rb * 16 + rrow + r;
            const float bv = bias1[o];
            float s = 0.f, s2 = 0.f;
            #pragma unroll
            for (int nb = 0; nb < 4; ++nb) {
                float val = acc[rb][nb][r] + bv;
                Y1bf[((size_t)b * H_ + o) * N_ + n0 + nb * 16 + col] = (__bf16)val;
                s += val;
                s2 = fmaf(val, val, s2);
            }
            #pragma unroll
            for (int delta = 1; delta < 16; delta <<= 1) {
                s  += __shfl_xor(s, delta);
                s2 += __shfl_xor(s2, delta);
            }
            if (col == 0) {
                partS [(size_t)o * NBLK + pid] = s;
                partS2[(size_t)o * NBLK + pid] = s2;
            }
        }
    }
}

// ------------------------------------------- reduce partials -> scale/shift
__global__ __launch_bounds__(256) void reduce_stats(const float* __restrict__ partS,
                                                    const float* __restrict__ partS2,
                                                    const float* __restrict__ g,
                                                    const float* __restrict__ beta,
                                                    float* __restrict__ sc,
                                                    float* __restrict__ sh) {
    const int c = blockIdx.x;
    const int t = threadIdx.x;
    double s = 0.0, s2 = 0.0;
    #pragma unroll
    for (int i = t; i < NBLK; i += 256) {
        s  += (double)partS [(size_t)c * NBLK + i];
        s2 += (double)partS2[(size_t)c * NBLK + i];
    }
    __shared__ double ls[256], ls2[256];
    ls[t] = s; ls2[t] = s2;
    __syncthreads();
    for (int off = 128; off > 0; off >>= 1) {
        if (t < off) { ls[t] += ls[t + off]; ls2[t] += ls2[t + off]; }
        __syncthreads();
    }
    if (t == 0) {
        const double cnt = (double)B_ * N_;
        double mean = ls[0] / cnt;
        double var  = ls2[0] / cnt - mean * mean;
        float rstd  = (float)(1.0 / sqrt(var + (double)BNEPS));
        float scale = rstd * g[c];
        sc[c] = scale;
        sh[c] = beta[c] - (float)mean * scale;
    }
}

// ------------------------------------------- GEMM2: BN1+ReLU on load, bf16 in/out,
// in-place on the bf16 panel, 2-deep pipelined staging, fused BN partials
__global__ __launch_bounds__(256, 2) void gemm2_kernel(const bf16x8* __restrict__ W2f,
                                                       const float* __restrict__ bias2,
                                                       const float* __restrict__ sc1,
                                                       const float* __restrict__ sh1,
                                                       __bf16* __restrict__ Ybf,
                                                       float* __restrict__ partS,
                                                       float* __restrict__ partS2) {
    __shared__ __align__(16) unsigned short Bfrag[2][4][64][8];
    __shared__ float scs[H_], shs[H_];

    const int b  = blockIdx.y;
    const int n0 = blockIdx.x * TJ;
    const int t  = threadIdx.x;
    const int wave = t >> 6, lane = t & 63;
    const int pid  = b * (N_ / TJ) + blockIdx.x;

    scs[t] = sc1[t];
    shs[t] = sh1[t];
    __syncthreads();

    const int j = t >> 2, q = t & 3;
    __bf16* Yb = Ybf + (size_t)b * H_ * N_;
    const __bf16* src = Yb + n0 + j;
    uint4* dstB[2] = { (uint4*)&Bfrag[0][j >> 4][q * 16 + (j & 15)][0],
                       (uint4*)&Bfrag[1][j >> 4][q * 16 + (j & 15)][0] };

    auto issue = [&](int kc, float L[8]) {
        #pragma unroll
        for (int e = 0; e < 8; ++e)
            L[e] = (float)src[(size_t)(kc * 32 + q * 8 + e) * N_];
    };
    auto packwrite = [&](int kc, const float L[8], uint4* dst) {
        union { __bf16 h[8]; uint4 u4; } pk;
        #pragma unroll
        for (int e = 0; e < 8; ++e) {
            const int c = kc * 32 + q * 8 + e;
            pk.h[e] = (__bf16)fmaxf(fmaf(L[e], scs[c], shs[c]), 0.0f);
        }
        *dst = pk.u4;
    };

    f32x4 acc[4][4];
    #pragma unroll
    for (int rb = 0; rb < 4; ++rb)
        #pragma unroll
        for (int nb = 0; nb < 4; ++nb) acc[rb][nb] = (f32x4){0.f, 0.f, 0.f, 0.f};

    float L[8];
    bf16x8 af[4], afn[4];
    issue(0, L);
    #pragma unroll
    for (int rb = 0; rb < 4; ++rb)
        af[rb] = W2f[((size_t)0 * 16 + wave * 4 + rb) * 64 + lane];
    packwrite(0, L, dstB[0]);
    __syncthreads();

    #pragma unroll
    for (int kc = 0; kc < H_ / 32; ++kc) {
        constexpr int NK = H_ / 32;
        float Ln[8];
        if (kc + 1 < NK) {
            issue(kc + 1, Ln);
            #pragma unroll
            for (int rb = 0; rb < 4; ++rb)
                afn[rb] = W2f[((size_t)(kc + 1) * 16 + wave * 4 + rb) * 64 + lane];
        }
        bf16x8 bfr[4];
        #pragma unroll
        for (int nb = 0; nb < 4; ++nb)
            bfr[nb] = *reinterpret_cast<const bf16x8*>(&Bfrag[kc & 1][nb][lane][0]);
        #pragma unroll
        for (int rb = 0; rb < 4; ++rb)
            #pragma unroll
            for (int nb = 0; nb < 4; ++nb)
                acc[rb][nb] = __builtin_amdgcn_mfma_f32_16x16x32_bf16(af[rb], bfr[nb],
                                                                      acc[rb][nb], 0, 0, 0);
        if (kc + 1 < NK) {
            packwrite(kc + 1, Ln, dstB[(kc + 1) & 1]);
            #pragma unroll
            for (int rb = 0; rb < 4; ++rb) af[rb] = afn[rb];
        }
        __syncthreads();
    }

    const int rrow = (lane >> 4) * 4, col = lane & 15;
    #pragma unroll
    for (int rb = 0; rb < 4; ++rb) {
        #pragma unroll
        for (int r = 0; r < 4; ++r) {
            const int o = wave * 64 + rb * 16 + rrow + r;
            const float bv = bias2[o];
            float s = 0.f, s2 = 0.f;
            #pragma unroll
            for (int nb = 0; nb < 4; ++nb) {
                float val = acc[rb][nb][r] + bv;
                Yb[(size_t)o * N_ + n0 + nb * 16 + col] = (__bf16)val;
                s += val;
                s2 = fmaf(val, val, s2);
            }
            #pragma unroll
            for (int delta = 1; delta < 16; delta <<= 1) {
                s  += __shfl_xor(s, delta);
                s2 += __shfl_xor(s2, delta);
            }
            if (col == 0) {
                partS [(size_t)o * NBLK + pid] = s;
                partS2[(size_t)o * NBLK + pid] = s2;
            }
        }
    }
}

// ------------------------------------------- final BN2+ReLU: bf16 in -> f32 out
__global__ __launch_bounds__(256) void bnrelu_kernel(const __bf16* __restrict__ Ybf,
                                                     float* __restrict__ out,
                                                     const float* __restrict__ sc,
                                                     const float* __restrict__ sh) {
    const size_t total8 = (size_t)B_ * H_ * N_ / 8;
    const size_t stride = (size_t)gridDim.x * 256;
    for (size_t i = (size_t)blockIdx.x * 256 + threadIdx.x; i < total8; i += stride) {
        bf16x8 v = ((const bf16x8*)Ybf)[i];
        const int c = (int)((i / (N_ / 8)) % H_);
        const float a = sc[c], d = sh[c];
        float4 lo, hi;
        lo.x = fmaxf(fmaf((float)v[0], a, d), 0.f);
        lo.y = fmaxf(fmaf((float)v[1], a, d), 0.f);
        lo.z = fmaxf(fmaf((float)v[2], a, d), 0.f);
        lo.w = fmaxf(fmaf((float)v[3], a, d), 0.f);
        hi.x = fmaxf(fmaf((float)v[4], a, d), 0.f);
        hi.y = fmaxf(fmaf((float)v[5], a, d), 0.f);
        hi.z = fmaxf(fmaf((float)v[6], a, d), 0.f);
        hi.w = fmaxf(fmaf((float)v[7], a, d), 0.f);
        ((float4*)out)[i * 2]     = lo;
        ((float4*)out)[i * 2 + 1] = hi;
    }
}

// ---------------------------------------------------------------- launch
extern "C" void kernel_launch(void* const* d_in, const int* in_sizes, int n_in,
                              void* d_out, int out_size, void* d_ws, size_t ws_size,
                              hipStream_t stream) {
    const float* xyz1    = (const float*)d_in[0];
    const float* xyz2    = (const float*)d_in[1];
    const float* points1 = (const float*)d_in[2];
    const float* points2 = (const float*)d_in[3];
    const float* W1      = (const float*)d_in[4];
    const float* b1      = (const float*)d_in[5];
    const float* g1      = (const float*)d_in[6];
    const float* beta1   = (const float*)d_in[7];
    const float* W2      = (const float*)d_in[8];
    const float* b2      = (const float*)d_in[9];
    const float* g2      = (const float*)d_in[10];
    const float* beta2   = (const float*)d_in[11];
    float* out = (float*)d_out;

    char* ws = (char*)d_ws;
    size_t off = 0;
    float* sc1 = (float*)(ws + off);  off += H_ * 4;
    float* sh1 = (float*)(ws + off);  off += H_ * 4;
    float* sc2 = (float*)(ws + off);  off += H_ * 4;
    float* sh2 = (float*)(ws + off);  off += H_ * 4;
    __bf16* p2t = (__bf16*)(ws + off); off += (size_t)B_ * M_ * C2_ * 2;     // 8.4 MB
    unsigned short* W1p = (unsigned short*)(ws + off); off += (size_t)H_ * CIN_ * 2;
    unsigned short* W2p = (unsigned short*)(ws + off); off += (size_t)H_ * H_ * 2;
    float* partS  = (float*)(ws + off); off += (size_t)H_ * NBLK * 4;        // 1 MB
    float* partS2 = (float*)(ws + off); off += (size_t)H_ * NBLK * 4;        // 1 MB
    __bf16* ybf   = (__bf16*)(ws + off); off += (size_t)B_ * H_ * N_ * 2;    // 33.5 MB

    tp2_kernel<<<dim3(C2_ / 32, M_ / 32, B_), 256, 0, stream>>>(points2, p2t);
    packW_kernel<<<(CIN_ / 32 * 16 * 64 + 255) / 256, 256, 0, stream>>>(W1, W1p, CIN_);
    packW_kernel<<<(H_ / 32 * 16 * 64 + 255) / 256, 256, 0, stream>>>(W2, W2p, H_);

    knn_gemm1_kernel<<<dim3(N_ / TJ, B_), 256, 0, stream>>>(xyz1, xyz2, points1, p2t,
                                                            (const bf16x8*)W1p, b1,
                                                            ybf, partS, partS2);
    reduce_stats<<<H_, 256, 0, stream>>>(partS, partS2, g1, beta1, sc1, sh1);
    gemm2_kernel<<<dim3(N_ / TJ, B_), 256, 0, stream>>>((const bf16x8*)W2p, b2, sc1, sh1,
                                                        ybf, partS, partS2);
    reduce_stats<<<H_, 256, 0, stream>>>(partS, partS2, g2, beta2, sc2, sh2);
    bnrelu_kernel<<<4096, 256, 0, stream>>>(ybf, out, sc2, sh2);
}